// Round 15
// baseline (1831.369 us; speedup 1.0000x reference)
//
#include <hip/hip_runtime.h>
#include <stdint.h>

// SetAbstraction (PointNet++): B=4, N=8192, C=128, S=2048, K=32, R=0.1
// Numerics locked (R5 passed, absmax 0.0156):
//  - FPS: f32, d = ((dx*dx + dy*dy) + dz*dz) mul/add LTR (np.sum order)
//  - grouping: sq = (cc+pp) - 2*dot, dot = fma(cz,z, fma(cy,y, cx*x)) (BLAS)
//  - MLP: bf16 MFMA
// R23 = R22 + ONE isolated change in the kfps loop: winner-coords broadcast.
// The serial chain had two DEPENDENT LDS reads (sAtom -> far -> sp[far]).
// Now each wave's cached-winner lane republishes its candidate coords to
// sCand[t&1][wv] every iteration (pre-barrier, off-chain); readers fetch
// sCand[t&1][lane&15] CONCURRENTLY with sAtom and select via 3 readlanes
// (wstar = slot>>9). Chain ~240cy -> ~150cy (~75us over 2047 iters).
// This was confounded inside R10 (bundled with the fast path R13 showed
// costs ~117us); tested here in isolation on the best base. Exactly one
// winner lane exists per wave after each reduce (unique PK); win persists
// across skips (same invariant as cachedKey); parity double-buffer; t=1
// forced update initializes all parity-1 entries. Else R22-verbatim.

typedef unsigned short u16;
typedef unsigned long long u64;
typedef __bf16 bf16x8 __attribute__((ext_vector_type(8)));
typedef float f32x4 __attribute__((ext_vector_type(4)));
typedef float f32x2 __attribute__((ext_vector_type(2)));

#define NB 4
#define NPTS 8192
#define CH 128
#define SPTS 2048
#define KN 32
#define CINP 160   // 131 padded to 160 (5 k-steps of 32)
#define GCAP 1280  // candidate-list capacity per wave (T~450 typ.)

__device__ __forceinline__ u16 f2b(float f) {  // f32 -> bf16 RNE
    unsigned x = __float_as_uint(f);
    unsigned r = (x + 0x7fffu + ((x >> 16) & 1u)) >> 16;
    return (u16)r;
}
__device__ __forceinline__ u64 umin64(u64 a, u64 b) { return a < b ? a : b; }
// spread 3 bits to positions 0,3,6 (8^3 morton component)
__device__ __forceinline__ int mort3(int v) {
    return (v & 1) | ((v & 2) << 2) | ((v & 4) << 4);
}
// spread 4 bits to positions 0,3,6,9 (16^3 morton component)
__device__ __forceinline__ int mort4(int v) {
    return (v & 1) | ((v & 2) << 2) | ((v & 4) << 4) | ((v & 8) << 6);
}

template <int CTRL>
__device__ __forceinline__ u64 dpp_max64(u64 k) {
    unsigned lo = (unsigned)k, hi = (unsigned)(k >> 32);
    unsigned mlo = (unsigned)__builtin_amdgcn_update_dpp((int)lo, (int)lo, CTRL, 0xF, 0xF, false);
    unsigned mhi = (unsigned)__builtin_amdgcn_update_dpp((int)hi, (int)hi, CTRL, 0xF, 0xF, false);
    u64 m = ((u64)mhi << 32) | mlo;
    return m > k ? m : k;
}
// uint-bits max (== float max for non-negative floats)
template <int CTRL>
__device__ __forceinline__ unsigned dpp_maxu(unsigned v) {
    unsigned mv = (unsigned)__builtin_amdgcn_update_dpp((int)v, (int)v, CTRL, 0xF, 0xF, false);
    return mv > v ? mv : v;
}

// ------- 16^3 Morton counting sort + sorted |p|^2 + 8^3 bin-base export -------
__global__ __launch_bounds__(256) void ksort(const float* __restrict__ coor,
                                             float* __restrict__ sxg,
                                             float* __restrict__ syg,
                                             float* __restrict__ szg,
                                             int* __restrict__ sog,
                                             float* __restrict__ spp,
                                             int* __restrict__ gbase) {
    __shared__ int hist[4096], base[4096];  // 32 KB
    __shared__ int partial[256];
    int b = blockIdx.x, tid = threadIdx.x;
    const float* cb = coor + b * 3 * NPTS;
    for (int i = tid; i < 4096; i += 256) hist[i] = 0;
    __syncthreads();
    int bins[32];
#pragma unroll 4
    for (int i = 0; i < 32; ++i) {
        int n = tid * 32 + i;
        float x = cb[n], y = cb[NPTS + n], z = cb[2 * NPTS + n];
        int bx = min(15, (int)(x * 16.0f));
        int by = min(15, (int)(y * 16.0f));
        int bz = min(15, (int)(z * 16.0f));
        int bin = mort4(bx) | (mort4(by) << 1) | (mort4(bz) << 2);
        bins[i] = bin;
        atomicAdd(&hist[bin], 1);
    }
    __syncthreads();
    // two-level exclusive prefix: 16 bins/thread, then scan 256 partials
    {
        int s = 0;
#pragma unroll 4
        for (int i = 0; i < 16; ++i) s += hist[tid * 16 + i];
        partial[tid] = s;
    }
    __syncthreads();
    if (tid == 0) {
        int acc = 0;
        for (int i = 0; i < 256; ++i) { int t = partial[i]; partial[i] = acc; acc += t; }
    }
    __syncthreads();
    {
        int acc = partial[tid];
#pragma unroll 4
        for (int i = 0; i < 16; ++i) {
            int idx = tid * 16 + i;
            base[idx] = acc;
            acc += hist[idx];
            hist[idx] = 0;
        }
    }
    __syncthreads();
    // export 8^3 bin bases: parent bin i = positions [base[8i], base[8(i+1)})
    gbase[b * 513 + tid] = base[tid * 8];
    gbase[b * 513 + 256 + tid] = base[(256 + tid) * 8];
    if (tid == 0) gbase[b * 513 + 512] = NPTS;
#pragma unroll 4
    for (int i = 0; i < 32; ++i) {
        int n = tid * 32 + i;
        int bin = bins[i];
        int pos = base[bin] + atomicAdd(&hist[bin], 1);
        float x = cb[n], y = cb[NPTS + n], z = cb[2 * NPTS + n];
        sxg[b * NPTS + pos] = x;
        syg[b * NPTS + pos] = y;
        szg[b * NPTS + pos] = z;
        sog[b * NPTS + pos] = n;
        spp[b * NPTS + pos] = __fadd_rn(__fadd_rn(__fmul_rn(x, x), __fmul_rn(y, y)),
                                        __fmul_rn(z, z));
    }
}

// ---- FPS mega-dispatch: blocks 0-3 FPS; 4-67 ktrans; 68-107 Wpad ----
__global__ __launch_bounds__(1024) void kfps(const float* __restrict__ sxg,
                                             const float* __restrict__ syg,
                                             const float* __restrict__ szg,
                                             const int* __restrict__ sog,
                                             int* __restrict__ fpsIdx,
                                             float* __restrict__ outCoor,
                                             const float* __restrict__ fea,
                                             const float* __restrict__ W,
                                             u16* __restrict__ feaT,
                                             u16* __restrict__ Wpad) {
    __shared__ float4 sp[NPTS];          // 128 KB (aux roles reuse as scratch)
    __shared__ unsigned sWin[SPTS];      // 8 KB
    __shared__ u64 sAtom[4];
    __shared__ float4 sCand[2][16];      // per-wave candidate coords (parity)
    __shared__ int slot0s;
    int bid = blockIdx.x;
    int tid = threadIdx.x;
    if (bid >= 4) {
        if (bid < 68) {
            // ---- transpose fea (B,C,N) f32 -> feaT (B,N,C) bf16; 4 tiles ----
            u16(*T)[130] = (u16(*)[130])sp;  // 33 KB within sp
            int base_t = (bid - 4) * 4;
#pragma unroll 1
            for (int k = 0; k < 4; ++k) {
                int tidx = base_t + k;
                int b = tidx >> 6, nt = tidx & 63;
                int n0 = nt * 128;
#pragma unroll 4
                for (int it = 0; it < 16; ++it) {
                    int idx = it * 1024 + tid;
                    int c = idx >> 7, nl = idx & 127;
                    T[nl][c] = f2b(fea[((size_t)(b * CH + c)) * NPTS + n0 + nl]);
                }
                __syncthreads();
#pragma unroll 4
                for (int it = 0; it < 16; ++it) {
                    int idx = it * 1024 + tid;
                    int nl = idx >> 7, c = idx & 127;
                    feaT[((size_t)(b * NPTS + n0 + nl)) * CH + c] = T[nl][c];
                }
                __syncthreads();
            }
        } else {
            // ---- W pad to bf16 ----
            int i = (bid - 68) * 1024 + tid;   // < 40960 = 256*160
            int d = i / CINP, k = i - d * CINP;
            Wpad[i] = (k < 131) ? f2b(W[d * 131 + k]) : (u16)0;
        }
        return;
    }
    // ================= FPS role =================
    int b = bid;
    int lane = tid & 63;
    int wv = tid >> 6;
    int li = lane & 15;
    const float* gx = sxg + b * NPTS;
    const float* gy = syg + b * NPTS;
    const float* gz = szg + b * NPTS;
    const int* go = sog + b * NPTS;
    f32x2 X2[4], Y2[4], Z2[4], D2[4];
    unsigned PK[8];
    int n0 = tid * 8;
    if (tid < 4) sAtom[tid] = 0;
    float lox, hix, loy, hiy, loz, hiz;  // per-lane bbox of this lane's 8 pts
#pragma unroll
    for (int j = 0; j < 8; ++j) {
        float x = gx[n0 + j], y = gy[n0 + j], z = gz[n0 + j];
        sp[n0 + j] = make_float4(x, y, z, 0.0f);
        X2[j >> 1][j & 1] = x; Y2[j >> 1][j & 1] = y; Z2[j >> 1][j & 1] = z;
        D2[j >> 1][j & 1] = 1e10f;
        int oi = go[n0 + j];
        PK[j] = ((unsigned)oi << 16) | (unsigned)(n0 + j);
        if (oi == 0) slot0s = n0 + j;
        if (j == 0) {
            lox = hix = x; loy = hiy = y; loz = hiz = z;
        } else {
            lox = fminf(lox, x); hix = fmaxf(hix, x);
            loy = fminf(loy, y); hiy = fmaxf(hiy, y);
            loz = fminf(loz, z); hiz = fmaxf(hiz, z);
        }
    }
    __syncthreads();
    float4 c0 = sp[slot0s];
    float fx = c0.x, fy = c0.y, fz = c0.z;
    if (tid == 0) sWin[0] = (unsigned)slot0s;  // origIdx 0 in high bits
    float lm = 3.4e38f;     // lane max D (exact); forces update on first iter
    u64 cachedKey = 1;      // any real key beats it
    bool win = false;       // am I my wave's cached-winner lane?
    float bX = 0.f, bY = 0.f, bZ = 0.f;  // winner lane: candidate coords
    for (int t = 1; t < SPTS; ++t) {
        // exact per-lane skip: min dist(c, lane bbox)^2 vs lane max D
        float ddx = fmaxf(0.0f, fmaxf(lox - fx, fx - hix));
        float ddy = fmaxf(0.0f, fmaxf(loy - fy, fy - hiy));
        float ddz = fmaxf(0.0f, fmaxf(loz - fz, fz - hiz));
        float dmin2 = ddx * ddx + ddy * ddy + ddz * ddz;
        if (__ballot(dmin2 * 0.9995f < lm) != 0ull) {  // any lane might change
            {
#pragma clang fp contract(off)
                f32x2 fx2 = {fx, fx}, fy2 = {fy, fy}, fz2 = {fz, fz};
#pragma unroll
                for (int i = 0; i < 4; ++i) {
                    f32x2 dx = X2[i] - fx2;
                    f32x2 dy = Y2[i] - fy2;
                    f32x2 dz = Z2[i] - fz2;
                    f32x2 s = (dx * dx + dy * dy) + dz * dz;  // per-elem RN, np order
                    D2[i] = __builtin_elementwise_min(D2[i], s);
                }
            }
            // thread argmax: packed value tree, then min-PK among ties
            f32x2 t01 = __builtin_elementwise_max(D2[0], D2[1]);
            f32x2 t23 = __builtin_elementwise_max(D2[2], D2[3]);
            f32x2 t03 = __builtin_elementwise_max(t01, t23);
            float m = fmaxf(t03[0], t03[1]);
            lm = m;  // lane max D, exact
            unsigned sel = 0xFFFFFFFFu;
#pragma unroll
            for (int j = 0; j < 8; ++j) {
                float dj = D2[j >> 1][j & 1];
                sel = (dj == m) ? (sel < PK[j] ? sel : PK[j]) : sel;
            }
            // wave value-max via DPP on float bits (all >= 0)
            unsigned mbits = __float_as_uint(m);
            unsigned r = mbits;
            r = dpp_maxu<0xB1>(r);    // quad_perm xor1
            r = dpp_maxu<0x4E>(r);    // quad_perm xor2
            r = dpp_maxu<0x141>(r);   // row_half_mirror
            r = dpp_maxu<0x140>(r);   // row_mirror
            r = dpp_maxu<0x142>(r);   // row_bcast:15
            r = dpp_maxu<0x143>(r);   // row_bcast:31
            unsigned wmaxb = (unsigned)__builtin_amdgcn_readlane((int)r, 63);
            u64 ball = __ballot(mbits == wmaxb);
            unsigned wpk;
            bool iw;
            if (__popcll(ball) == 1) {  // unique winner lane (common)
                int l = __ffsll(ball) - 1;
                wpk = (unsigned)__builtin_amdgcn_readlane((int)sel, l);
                iw = (mbits == wmaxb);
            } else {                    // rare: cross-lane value tie
                u64 kk = (mbits == wmaxb) ? (((u64)wmaxb << 32) | (unsigned)~sel) : 0ull;
                kk = dpp_max64<0xB1>(kk);
                kk = dpp_max64<0x4E>(kk);
                kk = dpp_max64<0x141>(kk);
                kk = dpp_max64<0x140>(kk);
                kk = dpp_max64<0x142>(kk);
                kk = dpp_max64<0x143>(kk);
                unsigned lo = (unsigned)__builtin_amdgcn_readlane((int)(unsigned)kk, 63);
                wpk = ~lo;
                iw = (mbits == wmaxb) && ((unsigned)~sel == lo);
            }
            win = iw;
            if (iw) {  // exactly one lane per wave: capture candidate coords
#pragma unroll
                for (int j = 0; j < 8; ++j) {
                    if (PK[j] == sel) {
                        bX = X2[j >> 1][j & 1];
                        bY = Y2[j >> 1][j & 1];
                        bZ = Z2[j >> 1][j & 1];
                    }
                }
            }
            cachedKey = ((u64)wmaxb << 32) | (unsigned)~wpk;
        }
        // cached-winner lane republishes coords (valid across skips, same
        // invariant as cachedKey); write lands before this iter's barrier.
        if (win) sCand[t & 1][wv] = make_float4(bX, bY, bZ, 0.0f);
        if (lane == 63) atomicMax(&sAtom[t & 3], cachedKey);
        if (tid == 0) sAtom[(t + 1) & 3] = 0;  // slot quiescent this window
        __syncthreads();
        u64 wk = sAtom[t & 3];            // broadcast b64
        float4 c4 = sCand[t & 1][li];     // CONCURRENT b128 (independent addr)
        unsigned pk = ~(unsigned)wk;
        int wstar = (int)((pk & 0xFFFFu) >> 9);  // 512 slots per wave
        fx = __uint_as_float((unsigned)__builtin_amdgcn_readlane((int)__float_as_uint(c4.x), wstar));
        fy = __uint_as_float((unsigned)__builtin_amdgcn_readlane((int)__float_as_uint(c4.y), wstar));
        fz = __uint_as_float((unsigned)__builtin_amdgcn_readlane((int)__float_as_uint(c4.z), wstar));
        if (tid == 0) sWin[t] = pk;
    }
    __syncthreads();
    // deferred flush
    for (int i = tid; i < SPTS; i += 1024) {
        unsigned pk = sWin[i];
        int slot = (int)(pk & 0xFFFFu);
        float4 c = sp[slot];
        fpsIdx[b * SPTS + i] = (int)(pk >> 16);
        float* oc = outCoor + b * 3 * SPTS + i;
        oc[0] = c.x; oc[SPTS] = c.y; oc[2 * SPTS] = c.z;
    }
}

// ---- grouping, spatially pruned (exact; 8^3 candidate bins). 1 wave/row ----
__global__ __launch_bounds__(256) void kgroup(const float* __restrict__ coor,
                                              const float* __restrict__ sxg,
                                              const float* __restrict__ syg,
                                              const float* __restrict__ szg,
                                              const int* __restrict__ sog,
                                              const float* __restrict__ spp,
                                              const int* __restrict__ gbase,
                                              const int* __restrict__ fpsIdx,
                                              int* __restrict__ gidxOut) {
    __shared__ u64 buf[4][256];
    __shared__ int posA[4][GCAP];
    __shared__ int cnt[4];
    int tid = threadIdx.x;
    int wv = tid >> 6, lane = tid & 63;
    if (tid < 4) cnt[tid] = 0;
    __syncthreads();
    int row = blockIdx.x * 4 + wv;
    int b = row >> 11, s = row & 2047;
    const float* cb = coor + b * 3 * NPTS;
    int n0 = fpsIdx[b * SPTS + s];
    float cx = cb[n0], cy = cb[NPTS + n0], cz = cb[2 * NPTS + n0];
    float cc = __fadd_rn(__fadd_rn(__fmul_rn(cx, cx), __fmul_rn(cy, cy)),
                         __fmul_rn(cz, cz));
    // candidate 8^3 Morton cells overlapping ball(c, 0.1 + fp margin)
    int bxlo = max(0, (int)floorf((cx - 0.1001f) * 8.0f));
    int bxhi = min(7, (int)floorf((cx + 0.1001f) * 8.0f));
    int bylo = max(0, (int)floorf((cy - 0.1001f) * 8.0f));
    int byhi = min(7, (int)floorf((cy + 0.1001f) * 8.0f));
    int bzlo = max(0, (int)floorf((cz - 0.1001f) * 8.0f));
    int bzhi = min(7, (int)floorf((cz + 0.1001f) * 8.0f));
    int nx = bxhi - bxlo + 1, ny = byhi - bylo + 1, nz = bzhi - bzlo + 1;
    int nbins = nx * ny * nz;  // <= 27
    const int* gb = gbase + b * 513;
    int lo = 0, len = 0;
    if (lane < nbins) {
        int lx = lane % nx;
        int rest = lane / nx;
        int ly = rest % ny;
        int lz = rest / ny;
        int bin = mort3(bxlo + lx) | (mort3(bylo + ly) << 1) | (mort3(bzlo + lz) << 2);
        lo = gb[bin];
        len = gb[bin + 1] - lo;  // counting sort => bins contiguous in position
    }
    // 64-lane inclusive scan of len -> flat offsets
    int v = len;
#pragma unroll
    for (int off = 1; off < 64; off <<= 1) {
        int u = __shfl_up(v, off);
        if (lane >= off) v += u;
    }
    int T = __shfl(v, 63);
    int pfe = v - len;
    bool fast = (T <= GCAP);  // wave-uniform
    if (fast) {
        for (int i = 0; i < len; ++i) posA[wv][pfe + i] = lo + i;
    }
    __syncthreads();  // publish posA across lanes (and waves' phases align)
    const float* bx_ = sxg + b * NPTS;
    const float* by_ = syg + b * NPTS;
    const float* bz_ = szg + b * NPTS;
    const int* bo_ = sog + b * NPTS;
    const float* bp_ = spp + b * NPTS;
    u64 mk = ~0ull;
    if (fast) {
        for (int j = lane; j < T; j += 64) {
            int p = posA[wv][j];
            float x = bx_[p], y = by_[p], z = bz_[p];
            float ppv = bp_[p];
            int oi = bo_[p];
            float dot = __fmaf_rn(cz, z, __fmaf_rn(cy, y, __fmul_rn(cx, x)));
            float sq = __fsub_rn(__fadd_rn(cc, ppv), __fmul_rn(2.0f, dot));
            unsigned ub = __float_as_uint(sq);
            ub ^= (ub >> 31) ? 0xFFFFFFFFu : 0x80000000u;
            u64 key = ((u64)ub << 32) | (unsigned)oi;
            mk = umin64(mk, key);
            if (sq <= 0.01f) {
                int p2 = atomicAdd(&cnt[wv], 1);
                if (p2 < 256) buf[wv][p2] = key;
            }
        }
    } else {  // overflow fallback: full scan (original path; pp inline)
        for (int n = lane; n < NPTS; n += 64) {
            float x = cb[n], y = cb[NPTS + n], z = cb[2 * NPTS + n];
            float ppv = __fadd_rn(__fadd_rn(__fmul_rn(x, x), __fmul_rn(y, y)),
                                  __fmul_rn(z, z));
            float dot = __fmaf_rn(cz, z, __fmaf_rn(cy, y, __fmul_rn(cx, x)));
            float sq = __fsub_rn(__fadd_rn(cc, ppv), __fmul_rn(2.0f, dot));
            unsigned ub = __float_as_uint(sq);
            ub ^= (ub >> 31) ? 0xFFFFFFFFu : 0x80000000u;
            u64 key = ((u64)ub << 32) | (unsigned)n;
            mk = umin64(mk, key);
            if (sq <= 0.01f) {
                int p2 = atomicAdd(&cnt[wv], 1);
                if (p2 < 256) buf[wv][p2] = key;
            }
        }
    }
#pragma unroll
    for (int off = 32; off > 0; off >>= 1) mk = umin64(mk, __shfl_xor(mk, off));
    int C = cnt[wv];
    if (C > 256) C = 256;
    int* go = gidxOut + row * KN;
    if (C <= 32) {
        if (lane < 32) {
            unsigned idx = (lane < C) ? (unsigned)buf[wv][lane] : (unsigned)mk;
            go[lane] = (int)idx;
        }
    } else {
        u64 e[4];
#pragma unroll
        for (int i = 0; i < 4; ++i) {
            int j2 = lane + (i << 6);
            e[i] = (j2 < C) ? buf[wv][j2] : ~0ull;
        }
        int cl = 0;
        unsigned sel = 0;
        for (int it = 0; it < 32; ++it) {
            u64 lb = ~0ull;
            int li = 0;
#pragma unroll
            for (int i = 0; i < 4; ++i) {
                bool f = (((cl >> i) & 1) == 0) && (e[i] < lb);
                lb = f ? e[i] : lb;
                li = f ? i : li;
            }
            u64 wmin = lb;
#pragma unroll
            for (int off = 32; off > 0; off >>= 1) wmin = umin64(wmin, __shfl_xor(wmin, off));
            u64 bal = __ballot(lb == wmin);
            int src = __ffsll((unsigned long long)bal) - 1;
            if (lane == src) cl |= (1 << li);
            if (lane == it) sel = (unsigned)wmin;
        }
        if (lane < 32) go[lane] = (int)sel;
    }
}

// ---------------- MLP + BN + ReLU + maxpool: 1 block per (b,s) row ----------------
__global__ __launch_bounds__(256) void kfeat(const float* __restrict__ coor,
                                             const u16* __restrict__ feaT,
                                             const u16* __restrict__ Wpad,
                                             const float* __restrict__ bias,
                                             const float* __restrict__ gamma,
                                             const float* __restrict__ beta,
                                             const float* __restrict__ bmean,
                                             const float* __restrict__ bvar,
                                             const int* __restrict__ fpsIdx,
                                             const int* __restrict__ gidx,
                                             float* __restrict__ outFea) {
    __shared__ u16 g[KN][168];
    int row = blockIdx.x;
    int b = row >> 11, s = row & 2047;
    int tid = threadIdx.x;
    {
        int k = tid >> 3, j = tid & 7;
        const float* cb = coor + b * 3 * NPTS;
        int nc = fpsIdx[b * SPTS + s];
        int nbr = gidx[row * KN + k];
        const uint4* f4 = (const uint4*)(feaT + (((size_t)b * NPTS + nbr) << 7));
        uint4* gr = (uint4*)&g[k][0];
        gr[j] = f4[j];
        gr[j + 8] = f4[j + 8];
        for (int c = 128 + j; c < CINP; c += 8) {
            u16 v = 0;
            if (c < 131) {
                int dim = c - 128;
                float pv = cb[dim * NPTS + nbr];
                float cv = cb[dim * NPTS + nc];
                v = f2b(__fdiv_rn(__fsub_rn(pv, cv), 0.1f));
            }
            g[k][c] = v;
        }
    }
    __syncthreads();
    int w = tid >> 6, lane = tid & 63;
    int mrow = lane & 15, q = lane >> 4;
    f32x4 acc[4][2] = {};
#pragma unroll
    for (int ks = 0; ks < 5; ++ks) {
        int kb = ks * 32 + q * 8;
        bf16x8 b0 = *(const bf16x8*)&g[mrow][kb];
        bf16x8 b1 = *(const bf16x8*)&g[mrow + 16][kb];
#pragma unroll
        for (int mt = 0; mt < 4; ++mt) {
            bf16x8 a = *(const bf16x8*)&Wpad[(size_t)(w * 64 + mt * 16 + mrow) * CINP + kb];
            acc[mt][0] = __builtin_amdgcn_mfma_f32_16x16x32_bf16(a, b0, acc[mt][0], 0, 0, 0);
            acc[mt][1] = __builtin_amdgcn_mfma_f32_16x16x32_bf16(a, b1, acc[mt][1], 0, 0, 0);
        }
    }
#pragma unroll
    for (int mt = 0; mt < 4; ++mt) {
#pragma unroll
        for (int r = 0; r < 4; ++r) {
            int m = w * 64 + mt * 16 + q * 4 + r;
            float ga = gamma[m], be = beta[m];
            float mu = bmean[m], va = bvar[m], bi = bias[m];
            float rs = 1.0f / sqrtf(va + 1e-5f);
            float h0 = acc[mt][0][r] + bi;
            h0 = fmaxf(ga * (h0 - mu) * rs + be, 0.0f);
            float h1 = acc[mt][1][r] + bi;
            h1 = fmaxf(ga * (h1 - mu) * rs + be, 0.0f);
            float v = fmaxf(h0, h1);
#pragma unroll
            for (int off = 1; off < 16; off <<= 1) v = fmaxf(v, __shfl_xor(v, off));
            if (mrow == 0) outFea[((size_t)(b * 256 + m)) * SPTS + s] = v;
        }
    }
}

extern "C" void kernel_launch(void* const* d_in, const int* in_sizes, int n_in,
                              void* d_out, int out_size, void* d_ws, size_t ws_size,
                              hipStream_t stream) {
    const float* coor = (const float*)d_in[0];
    const float* fea = (const float*)d_in[1];
    const float* W = (const float*)d_in[2];
    const float* bias = (const float*)d_in[3];
    const float* gamma = (const float*)d_in[4];
    const float* beta = (const float*)d_in[5];
    const float* bmean = (const float*)d_in[6];
    const float* bvar = (const float*)d_in[7];
    char* ws = (char*)d_ws;
    int* fpsIdx = (int*)ws;                              // 32 KB
    float* spp = (float*)(ws + 32768);                   // 128 KB
    int* gbase = (int*)(ws + 163840);                    // 16 KB (4 x 513 ints)
    int* gidx = (int*)(ws + 180224);                     // 1 MB
    u16* feaT = (u16*)(ws + 1228800);                    // 8 MB bf16
    u16* Wpad = (u16*)(ws + 9617408);                    // 80 KB bf16
    float* sxg = (float*)(ws + 9699328);                 // 128 KB
    float* syg = (float*)(ws + 9830400);                 // 128 KB
    float* szg = (float*)(ws + 9961472);                 // 128 KB
    int* sog = (int*)(ws + 10092544);                    // 128 KB
    float* outC = (float*)d_out;                         // (B,3,S) f32
    float* outF = outC + NB * 3 * SPTS;                  // (B,2C,S) f32

    ksort<<<NB, 256, 0, stream>>>(coor, sxg, syg, szg, sog, spp, gbase);
    kfps<<<108, 1024, 0, stream>>>(sxg, syg, szg, sog, fpsIdx, outC,
                                   fea, W, feaT, Wpad);
    kgroup<<<2048, 256, 0, stream>>>(coor, sxg, syg, szg, sog, spp, gbase,
                                     fpsIdx, gidx);
    kfeat<<<8192, 256, 0, stream>>>(coor, feaT, Wpad, bias, gamma, beta, bmean, bvar,
                                    fpsIdx, gidx, outF);
}

// Round 17
// 1462.138 us; speedup vs baseline: 1.2525x; 1.2525x over previous
//
#include <hip/hip_runtime.h>
#include <stdint.h>

// SetAbstraction (PointNet++): B=4, N=8192, C=128, S=2048, K=32, R=0.1
// Numerics locked (R5 passed, absmax 0.0156):
//  - FPS: f32, d = ((dx*dx + dy*dy) + dz*dz) mul/add LTR (np.sum order)
//  - grouping: sq = (cc+pp) - 2*dot, dot = fma(cz,z, fma(cy,y, cx*x)) (BLAS)
//  - MLP: bf16 MFMA
// R25 = R24 resubmit (infra failure last round; source byte-identical to
// R22, best measured: 1469us total / kfps 1233us in R14). Final structure:
// 16^3 Morton ksort (tight lane bboxes), kfps with per-lane exact skip +
// 4-slot rotating LDS atomicMax combine + prep overlap on idle CUs,
// spatially-pruned exact kgroup (<=27 candidate 8^3 bins), MFMA kfeat.

typedef unsigned short u16;
typedef unsigned long long u64;
typedef __bf16 bf16x8 __attribute__((ext_vector_type(8)));
typedef float f32x4 __attribute__((ext_vector_type(4)));
typedef float f32x2 __attribute__((ext_vector_type(2)));

#define NB 4
#define NPTS 8192
#define CH 128
#define SPTS 2048
#define KN 32
#define CINP 160   // 131 padded to 160 (5 k-steps of 32)
#define GCAP 1280  // candidate-list capacity per wave (T~450 typ.)

__device__ __forceinline__ u16 f2b(float f) {  // f32 -> bf16 RNE
    unsigned x = __float_as_uint(f);
    unsigned r = (x + 0x7fffu + ((x >> 16) & 1u)) >> 16;
    return (u16)r;
}
__device__ __forceinline__ u64 umin64(u64 a, u64 b) { return a < b ? a : b; }
// spread 3 bits to positions 0,3,6 (8^3 morton component)
__device__ __forceinline__ int mort3(int v) {
    return (v & 1) | ((v & 2) << 2) | ((v & 4) << 4);
}
// spread 4 bits to positions 0,3,6,9 (16^3 morton component)
__device__ __forceinline__ int mort4(int v) {
    return (v & 1) | ((v & 2) << 2) | ((v & 4) << 4) | ((v & 8) << 6);
}

template <int CTRL>
__device__ __forceinline__ u64 dpp_max64(u64 k) {
    unsigned lo = (unsigned)k, hi = (unsigned)(k >> 32);
    unsigned mlo = (unsigned)__builtin_amdgcn_update_dpp((int)lo, (int)lo, CTRL, 0xF, 0xF, false);
    unsigned mhi = (unsigned)__builtin_amdgcn_update_dpp((int)hi, (int)hi, CTRL, 0xF, 0xF, false);
    u64 m = ((u64)mhi << 32) | mlo;
    return m > k ? m : k;
}
// uint-bits max (== float max for non-negative floats)
template <int CTRL>
__device__ __forceinline__ unsigned dpp_maxu(unsigned v) {
    unsigned mv = (unsigned)__builtin_amdgcn_update_dpp((int)v, (int)v, CTRL, 0xF, 0xF, false);
    return mv > v ? mv : v;
}

// ------- 16^3 Morton counting sort + sorted |p|^2 + 8^3 bin-base export -------
__global__ __launch_bounds__(256) void ksort(const float* __restrict__ coor,
                                             float* __restrict__ sxg,
                                             float* __restrict__ syg,
                                             float* __restrict__ szg,
                                             int* __restrict__ sog,
                                             float* __restrict__ spp,
                                             int* __restrict__ gbase) {
    __shared__ int hist[4096], base[4096];  // 32 KB
    __shared__ int partial[256];
    int b = blockIdx.x, tid = threadIdx.x;
    const float* cb = coor + b * 3 * NPTS;
    for (int i = tid; i < 4096; i += 256) hist[i] = 0;
    __syncthreads();
    int bins[32];
#pragma unroll 4
    for (int i = 0; i < 32; ++i) {
        int n = tid * 32 + i;
        float x = cb[n], y = cb[NPTS + n], z = cb[2 * NPTS + n];
        int bx = min(15, (int)(x * 16.0f));
        int by = min(15, (int)(y * 16.0f));
        int bz = min(15, (int)(z * 16.0f));
        int bin = mort4(bx) | (mort4(by) << 1) | (mort4(bz) << 2);
        bins[i] = bin;
        atomicAdd(&hist[bin], 1);
    }
    __syncthreads();
    // two-level exclusive prefix: 16 bins/thread, then scan 256 partials
    {
        int s = 0;
#pragma unroll 4
        for (int i = 0; i < 16; ++i) s += hist[tid * 16 + i];
        partial[tid] = s;
    }
    __syncthreads();
    if (tid == 0) {
        int acc = 0;
        for (int i = 0; i < 256; ++i) { int t = partial[i]; partial[i] = acc; acc += t; }
    }
    __syncthreads();
    {
        int acc = partial[tid];
#pragma unroll 4
        for (int i = 0; i < 16; ++i) {
            int idx = tid * 16 + i;
            base[idx] = acc;
            acc += hist[idx];
            hist[idx] = 0;
        }
    }
    __syncthreads();
    // export 8^3 bin bases: parent bin i = positions [base[8i], base[8(i+1)})
    gbase[b * 513 + tid] = base[tid * 8];
    gbase[b * 513 + 256 + tid] = base[(256 + tid) * 8];
    if (tid == 0) gbase[b * 513 + 512] = NPTS;
#pragma unroll 4
    for (int i = 0; i < 32; ++i) {
        int n = tid * 32 + i;
        int bin = bins[i];
        int pos = base[bin] + atomicAdd(&hist[bin], 1);
        float x = cb[n], y = cb[NPTS + n], z = cb[2 * NPTS + n];
        sxg[b * NPTS + pos] = x;
        syg[b * NPTS + pos] = y;
        szg[b * NPTS + pos] = z;
        sog[b * NPTS + pos] = n;
        spp[b * NPTS + pos] = __fadd_rn(__fadd_rn(__fmul_rn(x, x), __fmul_rn(y, y)),
                                        __fmul_rn(z, z));
    }
}

// ---- FPS mega-dispatch: blocks 0-3 FPS (R15 verbatim); 4-67 ktrans; 68-107 Wpad ----
__global__ __launch_bounds__(1024) void kfps(const float* __restrict__ sxg,
                                             const float* __restrict__ syg,
                                             const float* __restrict__ szg,
                                             const int* __restrict__ sog,
                                             int* __restrict__ fpsIdx,
                                             float* __restrict__ outCoor,
                                             const float* __restrict__ fea,
                                             const float* __restrict__ W,
                                             u16* __restrict__ feaT,
                                             u16* __restrict__ Wpad) {
    __shared__ float4 sp[NPTS];          // 128 KB (aux roles reuse as scratch)
    __shared__ unsigned sWin[SPTS];      // 8 KB
    __shared__ u64 sAtom[4];
    __shared__ int slot0s;
    int bid = blockIdx.x;
    int tid = threadIdx.x;
    if (bid >= 4) {
        if (bid < 68) {
            // ---- transpose fea (B,C,N) f32 -> feaT (B,N,C) bf16; 4 tiles ----
            u16(*T)[130] = (u16(*)[130])sp;  // 33 KB within sp
            int base_t = (bid - 4) * 4;
#pragma unroll 1
            for (int k = 0; k < 4; ++k) {
                int tidx = base_t + k;
                int b = tidx >> 6, nt = tidx & 63;
                int n0 = nt * 128;
#pragma unroll 4
                for (int it = 0; it < 16; ++it) {
                    int idx = it * 1024 + tid;
                    int c = idx >> 7, nl = idx & 127;
                    T[nl][c] = f2b(fea[((size_t)(b * CH + c)) * NPTS + n0 + nl]);
                }
                __syncthreads();
#pragma unroll 4
                for (int it = 0; it < 16; ++it) {
                    int idx = it * 1024 + tid;
                    int nl = idx >> 7, c = idx & 127;
                    feaT[((size_t)(b * NPTS + n0 + nl)) * CH + c] = T[nl][c];
                }
                __syncthreads();
            }
        } else {
            // ---- W pad to bf16 ----
            int i = (bid - 68) * 1024 + tid;   // < 40960 = 256*160
            int d = i / CINP, k = i - d * CINP;
            Wpad[i] = (k < 131) ? f2b(W[d * 131 + k]) : (u16)0;
        }
        return;
    }
    // ================= FPS role (R15 verbatim) =================
    int b = bid;
    int lane = tid & 63;
    const float* gx = sxg + b * NPTS;
    const float* gy = syg + b * NPTS;
    const float* gz = szg + b * NPTS;
    const int* go = sog + b * NPTS;
    f32x2 X2[4], Y2[4], Z2[4], D2[4];
    unsigned PK[8];
    int n0 = tid * 8;
    if (tid < 4) sAtom[tid] = 0;
    float lox, hix, loy, hiy, loz, hiz;  // per-lane bbox of this lane's 8 pts
#pragma unroll
    for (int j = 0; j < 8; ++j) {
        float x = gx[n0 + j], y = gy[n0 + j], z = gz[n0 + j];
        sp[n0 + j] = make_float4(x, y, z, 0.0f);
        X2[j >> 1][j & 1] = x; Y2[j >> 1][j & 1] = y; Z2[j >> 1][j & 1] = z;
        D2[j >> 1][j & 1] = 1e10f;
        int oi = go[n0 + j];
        PK[j] = ((unsigned)oi << 16) | (unsigned)(n0 + j);
        if (oi == 0) slot0s = n0 + j;
        if (j == 0) {
            lox = hix = x; loy = hiy = y; loz = hiz = z;
        } else {
            lox = fminf(lox, x); hix = fmaxf(hix, x);
            loy = fminf(loy, y); hiy = fmaxf(hiy, y);
            loz = fminf(loz, z); hiz = fmaxf(hiz, z);
        }
    }
    __syncthreads();
    int far = slot0s;
    if (tid == 0) sWin[0] = (unsigned)slot0s;  // origIdx 0 in high bits
    float lm = 3.4e38f;     // lane max D (exact); forces update on first iter
    u64 cachedKey = 1;      // any real key beats it
    for (int t = 1; t < SPTS; ++t) {
        float4 c = sp[far];  // uniform addr -> broadcast ds_read_b128
        float fx = c.x, fy = c.y, fz = c.z;
        // exact per-lane skip: min dist(c, lane bbox)^2 vs lane max D
        float ddx = fmaxf(0.0f, fmaxf(lox - fx, fx - hix));
        float ddy = fmaxf(0.0f, fmaxf(loy - fy, fy - hiy));
        float ddz = fmaxf(0.0f, fmaxf(loz - fz, fz - hiz));
        float dmin2 = ddx * ddx + ddy * ddy + ddz * ddz;
        if (__ballot(dmin2 * 0.9995f < lm) != 0ull) {  // any lane might change
            {
#pragma clang fp contract(off)
                f32x2 fx2 = {fx, fx}, fy2 = {fy, fy}, fz2 = {fz, fz};
#pragma unroll
                for (int i = 0; i < 4; ++i) {
                    f32x2 dx = X2[i] - fx2;
                    f32x2 dy = Y2[i] - fy2;
                    f32x2 dz = Z2[i] - fz2;
                    f32x2 s = (dx * dx + dy * dy) + dz * dz;  // per-elem RN, np order
                    D2[i] = __builtin_elementwise_min(D2[i], s);
                }
            }
            // thread argmax: packed value tree, then min-PK among ties
            f32x2 t01 = __builtin_elementwise_max(D2[0], D2[1]);
            f32x2 t23 = __builtin_elementwise_max(D2[2], D2[3]);
            f32x2 t03 = __builtin_elementwise_max(t01, t23);
            float m = fmaxf(t03[0], t03[1]);
            lm = m;  // lane max D, exact
            unsigned sel = 0xFFFFFFFFu;
#pragma unroll
            for (int j = 0; j < 8; ++j) {
                float dj = D2[j >> 1][j & 1];
                sel = (dj == m) ? (sel < PK[j] ? sel : PK[j]) : sel;
            }
            // wave value-max via DPP on float bits (all >= 0)
            unsigned mbits = __float_as_uint(m);
            unsigned r = mbits;
            r = dpp_maxu<0xB1>(r);    // quad_perm xor1
            r = dpp_maxu<0x4E>(r);    // quad_perm xor2
            r = dpp_maxu<0x141>(r);   // row_half_mirror
            r = dpp_maxu<0x140>(r);   // row_mirror
            r = dpp_maxu<0x142>(r);   // row_bcast:15
            r = dpp_maxu<0x143>(r);   // row_bcast:31
            unsigned wmaxb = (unsigned)__builtin_amdgcn_readlane((int)r, 63);
            u64 ball = __ballot(mbits == wmaxb);
            unsigned wpk;
            if (__popcll(ball) == 1) {  // unique winner lane (common)
                int l = __ffsll(ball) - 1;
                wpk = (unsigned)__builtin_amdgcn_readlane((int)sel, l);
            } else {                    // rare: cross-lane value tie
                u64 kk = (mbits == wmaxb) ? (((u64)wmaxb << 32) | (unsigned)~sel) : 0ull;
                kk = dpp_max64<0xB1>(kk);
                kk = dpp_max64<0x4E>(kk);
                kk = dpp_max64<0x141>(kk);
                kk = dpp_max64<0x140>(kk);
                kk = dpp_max64<0x142>(kk);
                kk = dpp_max64<0x143>(kk);
                unsigned lo = (unsigned)__builtin_amdgcn_readlane((int)(unsigned)kk, 63);
                wpk = ~lo;
            }
            cachedKey = ((u64)wmaxb << 32) | (unsigned)~wpk;
        }
        if (lane == 63) atomicMax(&sAtom[t & 3], cachedKey);
        if (tid == 0) sAtom[(t + 1) & 3] = 0;  // slot quiescent this window
        __syncthreads();
        u64 wk = sAtom[t & 3];  // broadcast ds_read_b64
        unsigned pk = ~(unsigned)wk;
        far = (int)(pk & 0xFFFFu);
        if (tid == 0) sWin[t] = pk;
    }
    __syncthreads();
    // deferred flush
    for (int i = tid; i < SPTS; i += 1024) {
        unsigned pk = sWin[i];
        int slot = (int)(pk & 0xFFFFu);
        float4 c = sp[slot];
        fpsIdx[b * SPTS + i] = (int)(pk >> 16);
        float* oc = outCoor + b * 3 * SPTS + i;
        oc[0] = c.x; oc[SPTS] = c.y; oc[2 * SPTS] = c.z;
    }
}

// ---- grouping, spatially pruned (exact; 8^3 candidate bins). 1 wave/row ----
__global__ __launch_bounds__(256) void kgroup(const float* __restrict__ coor,
                                              const float* __restrict__ sxg,
                                              const float* __restrict__ syg,
                                              const float* __restrict__ szg,
                                              const int* __restrict__ sog,
                                              const float* __restrict__ spp,
                                              const int* __restrict__ gbase,
                                              const int* __restrict__ fpsIdx,
                                              int* __restrict__ gidxOut) {
    __shared__ u64 buf[4][256];
    __shared__ int posA[4][GCAP];
    __shared__ int cnt[4];
    int tid = threadIdx.x;
    int wv = tid >> 6, lane = tid & 63;
    if (tid < 4) cnt[tid] = 0;
    __syncthreads();
    int row = blockIdx.x * 4 + wv;
    int b = row >> 11, s = row & 2047;
    const float* cb = coor + b * 3 * NPTS;
    int n0 = fpsIdx[b * SPTS + s];
    float cx = cb[n0], cy = cb[NPTS + n0], cz = cb[2 * NPTS + n0];
    float cc = __fadd_rn(__fadd_rn(__fmul_rn(cx, cx), __fmul_rn(cy, cy)),
                         __fmul_rn(cz, cz));
    // candidate 8^3 Morton cells overlapping ball(c, 0.1 + fp margin)
    int bxlo = max(0, (int)floorf((cx - 0.1001f) * 8.0f));
    int bxhi = min(7, (int)floorf((cx + 0.1001f) * 8.0f));
    int bylo = max(0, (int)floorf((cy - 0.1001f) * 8.0f));
    int byhi = min(7, (int)floorf((cy + 0.1001f) * 8.0f));
    int bzlo = max(0, (int)floorf((cz - 0.1001f) * 8.0f));
    int bzhi = min(7, (int)floorf((cz + 0.1001f) * 8.0f));
    int nx = bxhi - bxlo + 1, ny = byhi - bylo + 1, nz = bzhi - bzlo + 1;
    int nbins = nx * ny * nz;  // <= 27
    const int* gb = gbase + b * 513;
    int lo = 0, len = 0;
    if (lane < nbins) {
        int lx = lane % nx;
        int rest = lane / nx;
        int ly = rest % ny;
        int lz = rest / ny;
        int bin = mort3(bxlo + lx) | (mort3(bylo + ly) << 1) | (mort3(bzlo + lz) << 2);
        lo = gb[bin];
        len = gb[bin + 1] - lo;  // counting sort => bins contiguous in position
    }
    // 64-lane inclusive scan of len -> flat offsets
    int v = len;
#pragma unroll
    for (int off = 1; off < 64; off <<= 1) {
        int u = __shfl_up(v, off);
        if (lane >= off) v += u;
    }
    int T = __shfl(v, 63);
    int pfe = v - len;
    bool fast = (T <= GCAP);  // wave-uniform
    if (fast) {
        for (int i = 0; i < len; ++i) posA[wv][pfe + i] = lo + i;
    }
    __syncthreads();  // publish posA across lanes (and waves' phases align)
    const float* bx_ = sxg + b * NPTS;
    const float* by_ = syg + b * NPTS;
    const float* bz_ = szg + b * NPTS;
    const int* bo_ = sog + b * NPTS;
    const float* bp_ = spp + b * NPTS;
    u64 mk = ~0ull;
    if (fast) {
        for (int j = lane; j < T; j += 64) {
            int p = posA[wv][j];
            float x = bx_[p], y = by_[p], z = bz_[p];
            float ppv = bp_[p];
            int oi = bo_[p];
            float dot = __fmaf_rn(cz, z, __fmaf_rn(cy, y, __fmul_rn(cx, x)));
            float sq = __fsub_rn(__fadd_rn(cc, ppv), __fmul_rn(2.0f, dot));
            unsigned ub = __float_as_uint(sq);
            ub ^= (ub >> 31) ? 0xFFFFFFFFu : 0x80000000u;
            u64 key = ((u64)ub << 32) | (unsigned)oi;
            mk = umin64(mk, key);
            if (sq <= 0.01f) {
                int p2 = atomicAdd(&cnt[wv], 1);
                if (p2 < 256) buf[wv][p2] = key;
            }
        }
    } else {  // overflow fallback: full scan (original path; pp inline)
        for (int n = lane; n < NPTS; n += 64) {
            float x = cb[n], y = cb[NPTS + n], z = cb[2 * NPTS + n];
            float ppv = __fadd_rn(__fadd_rn(__fmul_rn(x, x), __fmul_rn(y, y)),
                                  __fmul_rn(z, z));
            float dot = __fmaf_rn(cz, z, __fmaf_rn(cy, y, __fmul_rn(cx, x)));
            float sq = __fsub_rn(__fadd_rn(cc, ppv), __fmul_rn(2.0f, dot));
            unsigned ub = __float_as_uint(sq);
            ub ^= (ub >> 31) ? 0xFFFFFFFFu : 0x80000000u;
            u64 key = ((u64)ub << 32) | (unsigned)n;
            mk = umin64(mk, key);
            if (sq <= 0.01f) {
                int p2 = atomicAdd(&cnt[wv], 1);
                if (p2 < 256) buf[wv][p2] = key;
            }
        }
    }
#pragma unroll
    for (int off = 32; off > 0; off >>= 1) mk = umin64(mk, __shfl_xor(mk, off));
    int C = cnt[wv];
    if (C > 256) C = 256;
    int* go = gidxOut + row * KN;
    if (C <= 32) {
        if (lane < 32) {
            unsigned idx = (lane < C) ? (unsigned)buf[wv][lane] : (unsigned)mk;
            go[lane] = (int)idx;
        }
    } else {
        u64 e[4];
#pragma unroll
        for (int i = 0; i < 4; ++i) {
            int j2 = lane + (i << 6);
            e[i] = (j2 < C) ? buf[wv][j2] : ~0ull;
        }
        int cl = 0;
        unsigned sel = 0;
        for (int it = 0; it < 32; ++it) {
            u64 lb = ~0ull;
            int li = 0;
#pragma unroll
            for (int i = 0; i < 4; ++i) {
                bool f = (((cl >> i) & 1) == 0) && (e[i] < lb);
                lb = f ? e[i] : lb;
                li = f ? i : li;
            }
            u64 wmin = lb;
#pragma unroll
            for (int off = 32; off > 0; off >>= 1) wmin = umin64(wmin, __shfl_xor(wmin, off));
            u64 bal = __ballot(lb == wmin);
            int src = __ffsll((unsigned long long)bal) - 1;
            if (lane == src) cl |= (1 << li);
            if (lane == it) sel = (unsigned)wmin;
        }
        if (lane < 32) go[lane] = (int)sel;
    }
}

// ---------------- MLP + BN + ReLU + maxpool: 1 block per (b,s) row ----------------
__global__ __launch_bounds__(256) void kfeat(const float* __restrict__ coor,
                                             const u16* __restrict__ feaT,
                                             const u16* __restrict__ Wpad,
                                             const float* __restrict__ bias,
                                             const float* __restrict__ gamma,
                                             const float* __restrict__ beta,
                                             const float* __restrict__ bmean,
                                             const float* __restrict__ bvar,
                                             const int* __restrict__ fpsIdx,
                                             const int* __restrict__ gidx,
                                             float* __restrict__ outFea) {
    __shared__ u16 g[KN][168];
    int row = blockIdx.x;
    int b = row >> 11, s = row & 2047;
    int tid = threadIdx.x;
    {
        int k = tid >> 3, j = tid & 7;
        const float* cb = coor + b * 3 * NPTS;
        int nc = fpsIdx[b * SPTS + s];
        int nbr = gidx[row * KN + k];
        const uint4* f4 = (const uint4*)(feaT + (((size_t)b * NPTS + nbr) << 7));
        uint4* gr = (uint4*)&g[k][0];
        gr[j] = f4[j];
        gr[j + 8] = f4[j + 8];
        for (int c = 128 + j; c < CINP; c += 8) {
            u16 v = 0;
            if (c < 131) {
                int dim = c - 128;
                float pv = cb[dim * NPTS + nbr];
                float cv = cb[dim * NPTS + nc];
                v = f2b(__fdiv_rn(__fsub_rn(pv, cv), 0.1f));
            }
            g[k][c] = v;
        }
    }
    __syncthreads();
    int w = tid >> 6, lane = tid & 63;
    int mrow = lane & 15, q = lane >> 4;
    f32x4 acc[4][2] = {};
#pragma unroll
    for (int ks = 0; ks < 5; ++ks) {
        int kb = ks * 32 + q * 8;
        bf16x8 b0 = *(const bf16x8*)&g[mrow][kb];
        bf16x8 b1 = *(const bf16x8*)&g[mrow + 16][kb];
#pragma unroll
        for (int mt = 0; mt < 4; ++mt) {
            bf16x8 a = *(const bf16x8*)&Wpad[(size_t)(w * 64 + mt * 16 + mrow) * CINP + kb];
            acc[mt][0] = __builtin_amdgcn_mfma_f32_16x16x32_bf16(a, b0, acc[mt][0], 0, 0, 0);
            acc[mt][1] = __builtin_amdgcn_mfma_f32_16x16x32_bf16(a, b1, acc[mt][1], 0, 0, 0);
        }
    }
#pragma unroll
    for (int mt = 0; mt < 4; ++mt) {
#pragma unroll
        for (int r = 0; r < 4; ++r) {
            int m = w * 64 + mt * 16 + q * 4 + r;
            float ga = gamma[m], be = beta[m];
            float mu = bmean[m], va = bvar[m], bi = bias[m];
            float rs = 1.0f / sqrtf(va + 1e-5f);
            float h0 = acc[mt][0][r] + bi;
            h0 = fmaxf(ga * (h0 - mu) * rs + be, 0.0f);
            float h1 = acc[mt][1][r] + bi;
            h1 = fmaxf(ga * (h1 - mu) * rs + be, 0.0f);
            float v = fmaxf(h0, h1);
#pragma unroll
            for (int off = 1; off < 16; off <<= 1) v = fmaxf(v, __shfl_xor(v, off));
            if (mrow == 0) outFea[((size_t)(b * 256 + m)) * SPTS + s] = v;
        }
    }
}

extern "C" void kernel_launch(void* const* d_in, const int* in_sizes, int n_in,
                              void* d_out, int out_size, void* d_ws, size_t ws_size,
                              hipStream_t stream) {
    const float* coor = (const float*)d_in[0];
    const float* fea = (const float*)d_in[1];
    const float* W = (const float*)d_in[2];
    const float* bias = (const float*)d_in[3];
    const float* gamma = (const float*)d_in[4];
    const float* beta = (const float*)d_in[5];
    const float* bmean = (const float*)d_in[6];
    const float* bvar = (const float*)d_in[7];
    char* ws = (char*)d_ws;
    int* fpsIdx = (int*)ws;                              // 32 KB
    float* spp = (float*)(ws + 32768);                   // 128 KB
    int* gbase = (int*)(ws + 163840);                    // 16 KB (4 x 513 ints)
    int* gidx = (int*)(ws + 180224);                     // 1 MB
    u16* feaT = (u16*)(ws + 1228800);                    // 8 MB bf16
    u16* Wpad = (u16*)(ws + 9617408);                    // 80 KB bf16
    float* sxg = (float*)(ws + 9699328);                 // 128 KB
    float* syg = (float*)(ws + 9830400);                 // 128 KB
    float* szg = (float*)(ws + 9961472);                 // 128 KB
    int* sog = (int*)(ws + 10092544);                    // 128 KB
    float* outC = (float*)d_out;                         // (B,3,S) f32
    float* outF = outC + NB * 3 * SPTS;                  // (B,2C,S) f32

    ksort<<<NB, 256, 0, stream>>>(coor, sxg, syg, szg, sog, spp, gbase);
    kfps<<<108, 1024, 0, stream>>>(sxg, syg, szg, sog, fpsIdx, outC,
                                   fea, W, feaT, Wpad);
    kgroup<<<2048, 256, 0, stream>>>(coor, sxg, syg, szg, sog, spp, gbase,
                                     fpsIdx, gidx);
    kfeat<<<8192, 256, 0, stream>>>(coor, feaT, Wpad, bias, gamma, beta, bmean, bvar,
                                    fpsIdx, gidx, outF);
}